// Round 12
// baseline (37.106 us; speedup 1.0000x reference)
//
#include <hip/hip_runtime.h>
#include <math.h>

// MPDO chain via MFMA + fp8 DELTA pair table + dual-chain ILP.
//   per b: edge = Pi_t M_t (64x64); out = log(tr(edge))
//
// Ledger: issue-work null (R8/R9), wave-count null (R4), split-k neg (R10),
// >L2 table neg (R7), byte-halving small (R11: -6%). Surviving theory:
// within-wave serial latency (relayout <- all 16 MFMAs <- relayout ...).
// R12: each wave runs TWO independent 16-step chains (halves of DIFFERENT
// b's) interleaved -> chain B fills chain A's dependency bubbles.
//   block=128 (2 waves), grid=B/2. wave w: first half of b_A=2blk+w,
//   second half of b_B=2blk+1-w. End: LDS exchange (R4-verified
//   tr(G0 G1) = sum G0^T[p,q] G1^T[q,p]), both waves emit one output.
// fp8-delta step (R11-verified): X <- X + D^T X, D = (1/16)P - I in e4m3,
// identity carried exactly in f32 C-operand. Scale 4^-64 -> log += 64*ln4.
// Fallback: ws < 2MB -> verified fp32 VALU kernel.

#define NSITES 64
#define NPAIRS 32

typedef float f32x16 __attribute__((ext_vector_type(16)));

// pack 4 f32 -> 1 dword of 4 fp8 e4m3
#define PACK4(P, A0, A1, A2, A3)                                               \
    asm("v_cvt_pk_fp8_f32 %0, %1, %2" : "=v"(P) : "v"(A0), "v"(A1));           \
    asm("v_cvt_pk_fp8_f32 %0, %1, %2 op_sel:[0,0,1]" : "+v"(P) : "v"(A2), "v"(A3));

// ---------- prep2f8: D^T = (1/16)P^T - I in fp8 (verified R11) ----------
__global__ __launch_bounds__(64)
void mpdo_prep2f8(const float* __restrict__ T, uint4* __restrict__ Mf8) {
    const int blk = blockIdx.x;
    const int pair = blk >> 4, combo = blk & 15;
    const int c0 = combo >> 2, c1 = combo & 3;
    const int ir0 = c0 >> 1, ic0 = c0 & 1, ir1 = c1 >> 1, ic1 = c1 & 1;
    const int lane = threadIdx.x;
    const int site0 = 2 * pair, site1 = 2 * pair + 1;

    __shared__ float sT0[256], sT1[256], sT2[256], sT3[256];
    __shared__ float sPA[16 * 64], sPB[16 * 64];

    *(float4*)&sT0[lane * 4] = *(const float4*)(T + ((size_t)(site0 * 2 + ir0)) * 256 + lane * 4);
    *(float4*)&sT1[lane * 4] = *(const float4*)(T + ((size_t)(site0 * 2 + ic0)) * 256 + lane * 4);
    *(float4*)&sT2[lane * 4] = *(const float4*)(T + ((size_t)(site1 * 2 + ir1)) * 256 + lane * 4);
    *(float4*)&sT3[lane * 4] = *(const float4*)(T + ((size_t)(site1 * 2 + ic1)) * 256 + lane * 4);
    __syncthreads();

    {
        const int i = lane >> 3, j = lane & 7;
        float pa[4][4], pb[4][4];
#pragma unroll
        for (int k = 0; k < 4; ++k)
#pragma unroll
            for (int jp = 0; jp < 4; ++jp) { pa[k][jp] = 0.0f; pb[k][jp] = 0.0f; }
#pragma unroll
        for (int a = 0; a < 8; ++a) {
            float4 x0 = *(const float4*)&sT0[(i * 8 + a) * 4];
            float4 y0 = *(const float4*)&sT2[(a * 8 + j) * 4];
            float4 x1 = *(const float4*)&sT1[(i * 8 + a) * 4];
            float4 y1 = *(const float4*)&sT3[(a * 8 + j) * 4];
            const float xk0[4] = {x0.x, x0.y, x0.z, x0.w};
            const float yj0[4] = {y0.x, y0.y, y0.z, y0.w};
            const float xk1[4] = {x1.x, x1.y, x1.z, x1.w};
            const float yj1[4] = {y1.x, y1.y, y1.z, y1.w};
#pragma unroll
            for (int k = 0; k < 4; ++k)
#pragma unroll
                for (int jp = 0; jp < 4; ++jp) {
                    pa[k][jp] = fmaf(xk0[k], yj0[jp], pa[k][jp]);
                    pb[k][jp] = fmaf(xk1[k], yj1[jp], pb[k][jp]);
                }
        }
#pragma unroll
        for (int k = 0; k < 4; ++k)
#pragma unroll
            for (int jp = 0; jp < 4; ++jp) {
                sPA[(k * 4 + jp) * 64 + lane] = pa[k][jp];
                sPB[(k * 4 + jp) * 64 + lane] = pb[k][jp];
            }
    }
    __syncthreads();

    const int h = lane >> 5, r = lane & 31, m = r & 7, j2 = r >> 3;
    float acc[8][8];
#pragma unroll
    for (int f = 0; f < 8; ++f)
#pragma unroll
        for (int e = 0; e < 8; ++e) acc[f][e] = 0.0f;

#pragma unroll 4
    for (int c = 0; c < 16; ++c) {
        float paf[8], pbe[8];
#pragma unroll
        for (int ti = 0; ti < 2; ++ti)
#pragma unroll
            for (int kt = 0; kt < 4; ++kt)
                paf[ti * 4 + kt] = sPA[c * 64 + (2 * kt + h) * 8 + (4 * ti + j2)];
#pragma unroll
        for (int e = 0; e < 8; ++e) pbe[e] = sPB[c * 64 + e * 8 + m];
#pragma unroll
        for (int f = 0; f < 8; ++f)
#pragma unroll
            for (int e = 0; e < 8; ++e)
                acc[f][e] = fmaf(paf[f], pbe[e], acc[f][e]);
    }

#pragma unroll
    for (int fp = 0; fp < 4; ++fp) {
        unsigned d[4];
#pragma unroll
        for (int s = 0; s < 2; ++s) {
            const int f = 2 * fp + s;
            const int ti = f >> 2, kt = f & 3;
            float Fv[8];
#pragma unroll
            for (int e = 0; e < 8; ++e) {
                float w = acc[f][e] * 0.0625f;
                if (32 * ti + r == 16 * kt + 8 * h + e) w -= 1.0f;
                Fv[e] = w;
            }
            PACK4(d[2 * s],     Fv[0], Fv[1], Fv[2], Fv[3])
            PACK4(d[2 * s + 1], Fv[4], Fv[5], Fv[6], Fv[7])
        }
        Mf8[((size_t)(pair * 16 + combo) * 4 + fp) * 64 + lane] =
            make_uint4(d[0], d[1], d[2], d[3]);
    }
}

// ---------- main: 2 waves/block, each wave = 2 independent 16-step chains ----------
__global__ __launch_bounds__(128, 1)
void mpdo_mfmaD(const int* __restrict__ qn, const uint4* __restrict__ Mf8,
                float* __restrict__ out) {
    const int blk = blockIdx.x;
    const int w = threadIdx.x >> 6;
    const int lane = threadIdx.x & 63;
    const int bA = 2 * blk + w;          // first half computed here
    const int bB = 2 * blk + (1 - w);    // second half computed here
    __shared__ float sL[2][64 * 65];

    const int pi = lane & 31;
    const int* qbA = qn + (size_t)bA * (2 * NSITES);
    const int* qbB = qn + (size_t)bB * (2 * NSITES);
    const int pcA = (qbA[2 * pi] << 3) | (qbA[64 + 2 * pi] << 2) |
                    (qbA[2 * pi + 1] << 1) | (qbA[64 + 2 * pi + 1]);
    const int pcB = (qbB[2 * pi] << 3) | (qbB[64 + 2 * pi] << 2) |
                    (qbB[2 * pi + 1] << 1) | (qbB[64 + 2 * pi + 1]);
    const unsigned long long a3 = __ballot(pcA & 8), a2 = __ballot(pcA & 4);
    const unsigned long long a1 = __ballot(pcA & 2), a0 = __ballot(pcA & 1);
    const unsigned long long b3 = __ballot(pcB & 8), b2 = __ballot(pcB & 4);
    const unsigned long long b1 = __ballot(pcB & 2), b0 = __ballot(pcB & 1);
    const int col = lane & 31, hh = lane >> 5;
    const int laneoff = lane * 16;

    f32x16 accA[2][2], accB[2][2];
#pragma unroll
    for (int rt = 0; rt < 2; ++rt)
#pragma unroll
        for (int ct = 0; ct < 2; ++ct)
#pragma unroll
            for (int g = 0; g < 16; ++g) {
                int row = (g & 3) + 8 * (g >> 2) + 4 * hh;
                float v = (rt == ct && row == col) ? 1.0f : 0.0f;
                accA[rt][ct][g] = v;
                accB[rt][ct][g] = v;
            }

    const char* Mbase = (const char*)Mf8;
    uint4 A0[4], A1[4], B0[4], B1[4];

#define COMBO(M3, M2, M1, M0, T_)                                              \
    ((int)(((((M3) >> (T_)) & 1ull) << 3) | ((((M2) >> (T_)) & 1ull) << 2) |   \
           ((((M1) >> (T_)) & 1ull) << 1) | (((M0) >> (T_)) & 1ull)))
#define LOADF(DST, CMB, PIDX)                                                  \
    {                                                                          \
        const char* nb_ = Mbase + (((size_t)(PIDX) * 16 + (CMB)) << 12) + laneoff; \
        _Pragma("unroll")                                                      \
        for (int fp = 0; fp < 4; ++fp)                                         \
            DST[fp] = *(const uint4*)(nb_ + fp * 1024);                        \
    }
#define A64(CUR, F)                                                            \
    (((F) & 1) ? (((unsigned long long)CUR[(F) >> 1].w << 32) | CUR[(F) >> 1].z) \
               : (((unsigned long long)CUR[(F) >> 1].y << 32) | CUR[(F) >> 1].x))

// fp8-delta step (verified R11), parameterized by accumulator + frag buffer
#define CHAIN_STEP(ACC, CUR)                                                  \
    {                                                                         \
        unsigned bf[4][2][2];                                                 \
        _Pragma("unroll")                                                     \
        for (int rt = 0; rt < 2; ++rt)                                        \
            _Pragma("unroll")                                                 \
            for (int ct = 0; ct < 2; ++ct) {                                  \
                unsigned u, v, u2, v2;                                        \
                PACK4(u,  ACC[rt][ct][0],  ACC[rt][ct][1],                    \
                          ACC[rt][ct][2],  ACC[rt][ct][3])                    \
                PACK4(v,  ACC[rt][ct][4],  ACC[rt][ct][5],                    \
                          ACC[rt][ct][6],  ACC[rt][ct][7])                    \
                asm("v_permlane32_swap_b32 %0, %1" : "+v"(u), "+v"(v));       \
                bf[2 * rt][ct][0] = u; bf[2 * rt][ct][1] = v;                 \
                PACK4(u2, ACC[rt][ct][8],  ACC[rt][ct][9],                    \
                          ACC[rt][ct][10], ACC[rt][ct][11])                   \
                PACK4(v2, ACC[rt][ct][12], ACC[rt][ct][13],                   \
                          ACC[rt][ct][14], ACC[rt][ct][15])                   \
                asm("v_permlane32_swap_b32 %0, %1" : "+v"(u2), "+v"(v2));     \
                bf[2 * rt + 1][ct][0] = u2; bf[2 * rt + 1][ct][1] = v2;       \
            }                                                                 \
        _Pragma("unroll")                                                     \
        for (int ti = 0; ti < 2; ++ti)                                        \
            _Pragma("unroll")                                                 \
            for (int tj = 0; tj < 2; ++tj) {                                  \
                f32x16 d = ACC[ti][tj];                                       \
                _Pragma("unroll")                                             \
                for (int kt = 0; kt < 4; ++kt) {                              \
                    unsigned long long av = A64(CUR, ti * 4 + kt);            \
                    unsigned long long bv =                                   \
                        ((unsigned long long)bf[kt][tj][1] << 32) |           \
                        bf[kt][tj][0];                                        \
                    d = __builtin_amdgcn_mfma_f32_32x32x16_fp8_fp8(           \
                        (long)av, (long)bv, d, 0, 0, 0);                      \
                }                                                             \
                ACC[ti][tj] = d;                                              \
            }                                                                 \
    }

    // prologue: step-0 frags. chainA = pairs 0..15, chainB = pairs 16..31
    LOADF(A0, COMBO(a3, a2, a1, a0, 0), 0)
    LOADF(B0, COMBO(b3, b2, b1, b0, 16), 16)

#define STEP2(T_, CA, NA, CB, NB)                                             \
    {                                                                         \
        int tn = (T_) + 1; if (tn > 15) tn = 15;                              \
        LOADF(NA, COMBO(a3, a2, a1, a0, tn), tn)                              \
        LOADF(NB, COMBO(b3, b2, b1, b0, 16 + tn), 16 + tn)                    \
        CHAIN_STEP(accA, CA)                                                  \
        CHAIN_STEP(accB, CB)                                                  \
    }

#pragma unroll 1
    for (int t = 0; t < 16; t += 2) {
        STEP2(t,     A0, A1, B0, B1)
        STEP2(t + 1, A1, A0, B1, B0)
    }
#undef STEP2
#undef CHAIN_STEP
#undef LOADF
#undef A64
#undef COMBO

    // ---- exchange: tr(G0 G1) = sum_{p,q} G0^T[p,q] * G1^T[q,p] ----
    // wave w holds: accA = G0^T(bA), accB = G1^T(bB). Write accB to sL[1-w];
    // bA's G1^T was written by wave 1-w into sL[w].
#pragma unroll
    for (int rt = 0; rt < 2; ++rt)
#pragma unroll
        for (int ct = 0; ct < 2; ++ct)
#pragma unroll
            for (int g = 0; g < 16; ++g) {
                int p = 32 * rt + (g & 3) + 8 * (g >> 2) + 4 * hh;
                int q = 32 * ct + col;
                sL[1 - w][p * 65 + q] = accB[rt][ct][g];
            }
    __syncthreads();
    {
        float dot = 0.0f;
#pragma unroll
        for (int rt = 0; rt < 2; ++rt)
#pragma unroll
            for (int ct = 0; ct < 2; ++ct)
#pragma unroll
                for (int g = 0; g < 16; ++g) {
                    int p = 32 * rt + (g & 3) + 8 * (g >> 2) + 4 * hh;
                    int q = 32 * ct + col;
                    dot = fmaf(accA[rt][ct][g], sL[w][q * 65 + p], dot);
                }
#pragma unroll
        for (int off = 32; off >= 1; off >>= 1)
            dot += __shfl_xor(dot, off, 64);
        if (lane == 0) {
            float tr = dot;
            float re = logf(fabsf(tr)) + 64.0f * 1.3862943611198906f; // undo 4^-64
            float im = (tr < 0.0f) ? 3.14159265358979323846f : 0.0f;
            out[2 * bA]     = re;
            out[2 * bA + 1] = im;
        }
    }
}

// ---------- fallback fp32 VALU kernel (verified R2) ----------
#define DD 8
#define KCHI 4
__global__ __launch_bounds__(64, 1)
void mpdo_chain(const int* __restrict__ qn, const float* __restrict__ T,
                float* __restrict__ out) {
    const int b = blockIdx.x;
    const int lane = threadIdx.x;
    __shared__ float sA[KCHI][DD][DD];
    __shared__ float sB[KCHI][DD][DD];
    float E[DD][DD];
#pragma unroll
    for (int i = 0; i < DD; ++i)
#pragma unroll
        for (int l = 0; l < DD; ++l) E[i][l] = (i * DD + l == lane) ? 1.0f : 0.0f;
    const int* qb = qn + (size_t)b * (2 * NSITES);
    int ir0 = qb[0], ic0 = qb[NSITES];
    float4 aP = *reinterpret_cast<const float4*>(T + (size_t)ir0 * 256 + lane * 4);
    float4 bP = *reinterpret_cast<const float4*>(T + (size_t)ic0 * 256 + lane * 4);
    const int li = lane >> 3, lj = lane & 7;
#pragma unroll 1
    for (int site = 0; site < NSITES; ++site) {
        __syncthreads();
        sA[0][li][lj] = 0.5f * aP.x; sA[1][li][lj] = 0.5f * aP.y;
        sA[2][li][lj] = 0.5f * aP.z; sA[3][li][lj] = 0.5f * aP.w;
        sB[0][li][lj] = 0.5f * bP.x; sB[1][li][lj] = 0.5f * bP.y;
        sB[2][li][lj] = 0.5f * bP.z; sB[3][li][lj] = 0.5f * bP.w;
        __syncthreads();
        if (site + 1 < NSITES) {
            int irn = qb[site + 1], icn = qb[NSITES + site + 1];
            aP = *reinterpret_cast<const float4*>(T + ((size_t)(site + 1) * 2 + irn) * 256 + lane * 4);
            bP = *reinterpret_cast<const float4*>(T + ((size_t)(site + 1) * 2 + icn) * 256 + lane * 4);
        }
        float Ep[DD][DD];
#pragma unroll
        for (int j = 0; j < DD; ++j)
#pragma unroll
            for (int m = 0; m < DD; ++m) Ep[j][m] = 0.0f;
#pragma unroll 1
        for (int k = 0; k < KCHI; ++k) {
            float tmp[DD][DD];
#pragma unroll
            for (int l = 0; l < DD; ++l) {
                const float4* bp = reinterpret_cast<const float4*>(&sB[k][l][0]);
                float4 b0 = bp[0], b1 = bp[1];
                float brow[DD] = {b0.x, b0.y, b0.z, b0.w, b1.x, b1.y, b1.z, b1.w};
                if (l == 0) {
#pragma unroll
                    for (int i = 0; i < DD; ++i)
#pragma unroll
                        for (int m = 0; m < DD; ++m) tmp[i][m] = E[i][0] * brow[m];
                } else {
#pragma unroll
                    for (int i = 0; i < DD; ++i)
#pragma unroll
                        for (int m = 0; m < DD; ++m)
                            tmp[i][m] = fmaf(E[i][l], brow[m], tmp[i][m]);
                }
            }
#pragma unroll
            for (int i = 0; i < DD; ++i) {
                const float4* ap = reinterpret_cast<const float4*>(&sA[k][i][0]);
                float4 a0 = ap[0], a1 = ap[1];
                float arow[DD] = {a0.x, a0.y, a0.z, a0.w, a1.x, a1.y, a1.z, a1.w};
#pragma unroll
                for (int j = 0; j < DD; ++j)
#pragma unroll
                    for (int m = 0; m < DD; ++m)
                        Ep[j][m] = fmaf(arow[j], tmp[i][m], Ep[j][m]);
            }
        }
#pragma unroll
        for (int i = 0; i < DD; ++i)
#pragma unroll
            for (int l = 0; l < DD; ++l) E[i][l] = Ep[i][l];
    }
    float diag = 0.0f;
#pragma unroll
    for (int i = 0; i < DD; ++i)
#pragma unroll
        for (int l = 0; l < DD; ++l) diag += (i * DD + l == lane) ? E[i][l] : 0.0f;
#pragma unroll
    for (int off = 32; off >= 1; off >>= 1) diag += __shfl_xor(diag, off, 64);
    if (lane == 0) {
        float tr = diag;
        out[2 * b]     = logf(fabsf(tr)) + 64.0f * 1.3862943611198906f;
        out[2 * b + 1] = (tr < 0.0f) ? 3.14159265358979323846f : 0.0f;
    }
}

extern "C" void kernel_launch(void* const* d_in, const int* in_sizes, int n_in,
                              void* d_out, int out_size, void* d_ws, size_t ws_size,
                              hipStream_t stream) {
    const int*   qn  = (const int*)d_in[0];
    const float* T   = (const float*)d_in[1];
    float*       out = (float*)d_out;
    const int B = in_sizes[0] / (2 * NSITES);
    const size_t WS_F8 = (size_t)NPAIRS * 16 * 4 * 64 * 16;  // 2 MB
    if (ws_size >= WS_F8 && (B % 2) == 0) {
        uint4* Mf8 = (uint4*)d_ws;
        mpdo_prep2f8<<<dim3(NPAIRS * 16), dim3(64), 0, stream>>>(T, Mf8);
        mpdo_mfmaD<<<dim3(B / 2), dim3(128), 0, stream>>>(qn, Mf8, out);
    } else {
        mpdo_chain<<<dim3(B), dim3(64), 0, stream>>>(qn, T, out);
    }
}

// Round 13
// 35.112 us; speedup vs baseline: 1.0568x; 1.0568x over previous
//
#include <hip/hip_runtime.h>
#include <math.h>

// MPDO chain via MFMA + fp8 DELTA pair table + SAME-WAVE dual chain.
//   per b: edge = Pi_t M_t (64x64); out = log(tr(edge))
//
// Ledger: issue-work null (R8/R9), wave-count null (R4), split-k neg (R10),
// >L2 table neg (R7), bytes small (R11 -6%), dual-chain-with-confounds neg
// (R12: 2-wave exchange + 2nd qn stream). R13 = clean dual-chain test:
//   ONE 64-thr wave per b computes chain0 = pairs 0..15 and chain1 = pairs
//   16..31 (same qn, same ballot masks), steps interleaved 1:1 -> chain1's
//   independent MFMAs fill chain0's dependency stalls. Grid/table traffic/
//   steps-per-wave identical to R11. End: R4-verified transpose-dot
//   tr(G0 G1) = sum G0^T[p,q] G1^T[q,p] via padded LDS, single barrier.
// fp8-delta step (R11-verified): X <- X + D^T X, D = (1/16)P - I in e4m3,
// identity carried exactly in f32 C-operand. Scale 4^-64 -> log += 64*ln4.
// Fallback: ws < 2MB -> verified fp32 VALU kernel.

#define NSITES 64
#define NPAIRS 32

typedef float f32x16 __attribute__((ext_vector_type(16)));

// pack 4 f32 -> 1 dword of 4 fp8 e4m3
#define PACK4(P, A0, A1, A2, A3)                                               \
    asm("v_cvt_pk_fp8_f32 %0, %1, %2" : "=v"(P) : "v"(A0), "v"(A1));           \
    asm("v_cvt_pk_fp8_f32 %0, %1, %2 op_sel:[0,0,1]" : "+v"(P) : "v"(A2), "v"(A3));

// ---------- prep2f8: D^T = (1/16)P^T - I in fp8 (verified R11) ----------
__global__ __launch_bounds__(64)
void mpdo_prep2f8(const float* __restrict__ T, uint4* __restrict__ Mf8) {
    const int blk = blockIdx.x;
    const int pair = blk >> 4, combo = blk & 15;
    const int c0 = combo >> 2, c1 = combo & 3;
    const int ir0 = c0 >> 1, ic0 = c0 & 1, ir1 = c1 >> 1, ic1 = c1 & 1;
    const int lane = threadIdx.x;
    const int site0 = 2 * pair, site1 = 2 * pair + 1;

    __shared__ float sT0[256], sT1[256], sT2[256], sT3[256];
    __shared__ float sPA[16 * 64], sPB[16 * 64];

    *(float4*)&sT0[lane * 4] = *(const float4*)(T + ((size_t)(site0 * 2 + ir0)) * 256 + lane * 4);
    *(float4*)&sT1[lane * 4] = *(const float4*)(T + ((size_t)(site0 * 2 + ic0)) * 256 + lane * 4);
    *(float4*)&sT2[lane * 4] = *(const float4*)(T + ((size_t)(site1 * 2 + ir1)) * 256 + lane * 4);
    *(float4*)&sT3[lane * 4] = *(const float4*)(T + ((size_t)(site1 * 2 + ic1)) * 256 + lane * 4);
    __syncthreads();

    {
        const int i = lane >> 3, j = lane & 7;
        float pa[4][4], pb[4][4];
#pragma unroll
        for (int k = 0; k < 4; ++k)
#pragma unroll
            for (int jp = 0; jp < 4; ++jp) { pa[k][jp] = 0.0f; pb[k][jp] = 0.0f; }
#pragma unroll
        for (int a = 0; a < 8; ++a) {
            float4 x0 = *(const float4*)&sT0[(i * 8 + a) * 4];
            float4 y0 = *(const float4*)&sT2[(a * 8 + j) * 4];
            float4 x1 = *(const float4*)&sT1[(i * 8 + a) * 4];
            float4 y1 = *(const float4*)&sT3[(a * 8 + j) * 4];
            const float xk0[4] = {x0.x, x0.y, x0.z, x0.w};
            const float yj0[4] = {y0.x, y0.y, y0.z, y0.w};
            const float xk1[4] = {x1.x, x1.y, x1.z, x1.w};
            const float yj1[4] = {y1.x, y1.y, y1.z, y1.w};
#pragma unroll
            for (int k = 0; k < 4; ++k)
#pragma unroll
                for (int jp = 0; jp < 4; ++jp) {
                    pa[k][jp] = fmaf(xk0[k], yj0[jp], pa[k][jp]);
                    pb[k][jp] = fmaf(xk1[k], yj1[jp], pb[k][jp]);
                }
        }
#pragma unroll
        for (int k = 0; k < 4; ++k)
#pragma unroll
            for (int jp = 0; jp < 4; ++jp) {
                sPA[(k * 4 + jp) * 64 + lane] = pa[k][jp];
                sPB[(k * 4 + jp) * 64 + lane] = pb[k][jp];
            }
    }
    __syncthreads();

    const int h = lane >> 5, r = lane & 31, m = r & 7, j2 = r >> 3;
    float acc[8][8];
#pragma unroll
    for (int f = 0; f < 8; ++f)
#pragma unroll
        for (int e = 0; e < 8; ++e) acc[f][e] = 0.0f;

#pragma unroll 4
    for (int c = 0; c < 16; ++c) {
        float paf[8], pbe[8];
#pragma unroll
        for (int ti = 0; ti < 2; ++ti)
#pragma unroll
            for (int kt = 0; kt < 4; ++kt)
                paf[ti * 4 + kt] = sPA[c * 64 + (2 * kt + h) * 8 + (4 * ti + j2)];
#pragma unroll
        for (int e = 0; e < 8; ++e) pbe[e] = sPB[c * 64 + e * 8 + m];
#pragma unroll
        for (int f = 0; f < 8; ++f)
#pragma unroll
            for (int e = 0; e < 8; ++e)
                acc[f][e] = fmaf(paf[f], pbe[e], acc[f][e]);
    }

#pragma unroll
    for (int fp = 0; fp < 4; ++fp) {
        unsigned d[4];
#pragma unroll
        for (int s = 0; s < 2; ++s) {
            const int f = 2 * fp + s;
            const int ti = f >> 2, kt = f & 3;
            float Fv[8];
#pragma unroll
            for (int e = 0; e < 8; ++e) {
                float w = acc[f][e] * 0.0625f;
                if (32 * ti + r == 16 * kt + 8 * h + e) w -= 1.0f;
                Fv[e] = w;
            }
            PACK4(d[2 * s],     Fv[0], Fv[1], Fv[2], Fv[3])
            PACK4(d[2 * s + 1], Fv[4], Fv[5], Fv[6], Fv[7])
        }
        Mf8[((size_t)(pair * 16 + combo) * 4 + fp) * 64 + lane] =
            make_uint4(d[0], d[1], d[2], d[3]);
    }
}

// ---------- main: 1 wave/b, TWO interleaved 16-step chains ----------
__global__ __launch_bounds__(64, 1)
void mpdo_mfmaDC(const int* __restrict__ qn, const uint4* __restrict__ Mf8,
                 float* __restrict__ out) {
    const int b = blockIdx.x;
    const int lane = threadIdx.x;
    __shared__ float sL[64 * 65];
    const int* qb = qn + (size_t)b * (2 * NSITES);
    const int pi = lane & 31;
    const int pc = (qb[2 * pi] << 3) | (qb[64 + 2 * pi] << 2) |
                   (qb[2 * pi + 1] << 1) | (qb[64 + 2 * pi + 1]);
    const unsigned long long m3 = __ballot(pc & 8);
    const unsigned long long m2 = __ballot(pc & 4);
    const unsigned long long m1 = __ballot(pc & 2);
    const unsigned long long m0 = __ballot(pc & 1);
    const int col = lane & 31, hh = lane >> 5;
    const int laneoff = lane * 16;

    f32x16 acc0[2][2], acc1[2][2];   // chain0: pairs 0..15; chain1: 16..31
#pragma unroll
    for (int rt = 0; rt < 2; ++rt)
#pragma unroll
        for (int ct = 0; ct < 2; ++ct)
#pragma unroll
            for (int g = 0; g < 16; ++g) {
                int row = (g & 3) + 8 * (g >> 2) + 4 * hh;
                float v = (rt == ct && row == col) ? 1.0f : 0.0f;
                acc0[rt][ct][g] = v;
                acc1[rt][ct][g] = v;
            }

    const char* Mbase = (const char*)Mf8;
    uint4 A0[4], A1[4], B0[4], B1[4];

#define COMBO(T_) ((int)(((((m3) >> (T_)) & 1ull) << 3) | ((((m2) >> (T_)) & 1ull) << 2) | \
                         ((((m1) >> (T_)) & 1ull) << 1) | (((m0) >> (T_)) & 1ull)))
#define LOADF(DST, PIDX)                                                       \
    {                                                                          \
        int c_ = COMBO(PIDX);                                                  \
        const char* nb_ = Mbase + (((size_t)(PIDX) * 16 + c_) << 12) + laneoff;\
        _Pragma("unroll")                                                      \
        for (int fp = 0; fp < 4; ++fp)                                         \
            DST[fp] = *(const uint4*)(nb_ + fp * 1024);                        \
    }
#define A64(CUR, F)                                                            \
    (((F) & 1) ? (((unsigned long long)CUR[(F) >> 1].w << 32) | CUR[(F) >> 1].z) \
               : (((unsigned long long)CUR[(F) >> 1].y << 32) | CUR[(F) >> 1].x))

// fp8-delta step (verified R11)
#define CHAIN_STEP(ACC, CUR)                                                  \
    {                                                                         \
        unsigned bf[4][2][2];                                                 \
        _Pragma("unroll")                                                     \
        for (int rt = 0; rt < 2; ++rt)                                        \
            _Pragma("unroll")                                                 \
            for (int ct = 0; ct < 2; ++ct) {                                  \
                unsigned u, v, u2, v2;                                        \
                PACK4(u,  ACC[rt][ct][0],  ACC[rt][ct][1],                    \
                          ACC[rt][ct][2],  ACC[rt][ct][3])                    \
                PACK4(v,  ACC[rt][ct][4],  ACC[rt][ct][5],                    \
                          ACC[rt][ct][6],  ACC[rt][ct][7])                    \
                asm("v_permlane32_swap_b32 %0, %1" : "+v"(u), "+v"(v));       \
                bf[2 * rt][ct][0] = u; bf[2 * rt][ct][1] = v;                 \
                PACK4(u2, ACC[rt][ct][8],  ACC[rt][ct][9],                    \
                          ACC[rt][ct][10], ACC[rt][ct][11])                   \
                PACK4(v2, ACC[rt][ct][12], ACC[rt][ct][13],                   \
                          ACC[rt][ct][14], ACC[rt][ct][15])                   \
                asm("v_permlane32_swap_b32 %0, %1" : "+v"(u2), "+v"(v2));     \
                bf[2 * rt + 1][ct][0] = u2; bf[2 * rt + 1][ct][1] = v2;       \
            }                                                                 \
        _Pragma("unroll")                                                     \
        for (int ti = 0; ti < 2; ++ti)                                        \
            _Pragma("unroll")                                                 \
            for (int tj = 0; tj < 2; ++tj) {                                  \
                f32x16 d = ACC[ti][tj];                                       \
                _Pragma("unroll")                                             \
                for (int kt = 0; kt < 4; ++kt) {                              \
                    unsigned long long av = A64(CUR, ti * 4 + kt);            \
                    unsigned long long bv =                                   \
                        ((unsigned long long)bf[kt][tj][1] << 32) |           \
                        bf[kt][tj][0];                                        \
                    d = __builtin_amdgcn_mfma_f32_32x32x16_fp8_fp8(           \
                        (long)av, (long)bv, d, 0, 0, 0);                      \
                }                                                             \
                ACC[ti][tj] = d;                                              \
            }                                                                 \
    }

    LOADF(A0, 0)
    LOADF(B0, 16)

#define STEP2(T_, CA, NA, CB, NB)                                             \
    {                                                                         \
        int tn = (T_) + 1; if (tn > 15) tn = 15;                              \
        LOADF(NA, tn)                                                         \
        LOADF(NB, 16 + tn)                                                    \
        CHAIN_STEP(acc0, CA)                                                  \
        CHAIN_STEP(acc1, CB)                                                  \
    }

#pragma unroll 1
    for (int t = 0; t < 16; t += 2) {
        STEP2(t,     A0, A1, B0, B1)
        STEP2(t + 1, A1, A0, B1, B0)
    }
#undef STEP2
#undef CHAIN_STEP
#undef LOADF
#undef A64
#undef COMBO

    // ---- same-wave exchange: tr(G0 G1) = sum_{p,q} G0^T[p,q] G1^T[q,p] ----
#pragma unroll
    for (int rt = 0; rt < 2; ++rt)
#pragma unroll
        for (int ct = 0; ct < 2; ++ct)
#pragma unroll
            for (int g = 0; g < 16; ++g) {
                int p = 32 * rt + (g & 3) + 8 * (g >> 2) + 4 * hh;
                int q = 32 * ct + col;
                sL[p * 65 + q] = acc1[rt][ct][g];
            }
    __syncthreads();
    {
        float dot = 0.0f;
#pragma unroll
        for (int rt = 0; rt < 2; ++rt)
#pragma unroll
            for (int ct = 0; ct < 2; ++ct)
#pragma unroll
                for (int g = 0; g < 16; ++g) {
                    int p = 32 * rt + (g & 3) + 8 * (g >> 2) + 4 * hh;
                    int q = 32 * ct + col;
                    dot = fmaf(acc0[rt][ct][g], sL[q * 65 + p], dot);
                }
#pragma unroll
        for (int off = 32; off >= 1; off >>= 1)
            dot += __shfl_xor(dot, off, 64);
        if (lane == 0) {
            float tr = dot;
            float re = logf(fabsf(tr)) + 64.0f * 1.3862943611198906f; // undo 4^-64
            float im = (tr < 0.0f) ? 3.14159265358979323846f : 0.0f;
            out[2 * b]     = re;
            out[2 * b + 1] = im;
        }
    }
}

// ---------- fallback fp32 VALU kernel (verified R2) ----------
#define DD 8
#define KCHI 4
__global__ __launch_bounds__(64, 1)
void mpdo_chain(const int* __restrict__ qn, const float* __restrict__ T,
                float* __restrict__ out) {
    const int b = blockIdx.x;
    const int lane = threadIdx.x;
    __shared__ float sA[KCHI][DD][DD];
    __shared__ float sB[KCHI][DD][DD];
    float E[DD][DD];
#pragma unroll
    for (int i = 0; i < DD; ++i)
#pragma unroll
        for (int l = 0; l < DD; ++l) E[i][l] = (i * DD + l == lane) ? 1.0f : 0.0f;
    const int* qb = qn + (size_t)b * (2 * NSITES);
    int ir0 = qb[0], ic0 = qb[NSITES];
    float4 aP = *reinterpret_cast<const float4*>(T + (size_t)ir0 * 256 + lane * 4);
    float4 bP = *reinterpret_cast<const float4*>(T + (size_t)ic0 * 256 + lane * 4);
    const int li = lane >> 3, lj = lane & 7;
#pragma unroll 1
    for (int site = 0; site < NSITES; ++site) {
        __syncthreads();
        sA[0][li][lj] = 0.5f * aP.x; sA[1][li][lj] = 0.5f * aP.y;
        sA[2][li][lj] = 0.5f * aP.z; sA[3][li][lj] = 0.5f * aP.w;
        sB[0][li][lj] = 0.5f * bP.x; sB[1][li][lj] = 0.5f * bP.y;
        sB[2][li][lj] = 0.5f * bP.z; sB[3][li][lj] = 0.5f * bP.w;
        __syncthreads();
        if (site + 1 < NSITES) {
            int irn = qb[site + 1], icn = qb[NSITES + site + 1];
            aP = *reinterpret_cast<const float4*>(T + ((size_t)(site + 1) * 2 + irn) * 256 + lane * 4);
            bP = *reinterpret_cast<const float4*>(T + ((size_t)(site + 1) * 2 + icn) * 256 + lane * 4);
        }
        float Ep[DD][DD];
#pragma unroll
        for (int j = 0; j < DD; ++j)
#pragma unroll
            for (int m = 0; m < DD; ++m) Ep[j][m] = 0.0f;
#pragma unroll 1
        for (int k = 0; k < KCHI; ++k) {
            float tmp[DD][DD];
#pragma unroll
            for (int l = 0; l < DD; ++l) {
                const float4* bp = reinterpret_cast<const float4*>(&sB[k][l][0]);
                float4 b0 = bp[0], b1 = bp[1];
                float brow[DD] = {b0.x, b0.y, b0.z, b0.w, b1.x, b1.y, b1.z, b1.w};
                if (l == 0) {
#pragma unroll
                    for (int i = 0; i < DD; ++i)
#pragma unroll
                        for (int m = 0; m < DD; ++m) tmp[i][m] = E[i][0] * brow[m];
                } else {
#pragma unroll
                    for (int i = 0; i < DD; ++i)
#pragma unroll
                        for (int m = 0; m < DD; ++m)
                            tmp[i][m] = fmaf(E[i][l], brow[m], tmp[i][m]);
                }
            }
#pragma unroll
            for (int i = 0; i < DD; ++i) {
                const float4* ap = reinterpret_cast<const float4*>(&sA[k][i][0]);
                float4 a0 = ap[0], a1 = ap[1];
                float arow[DD] = {a0.x, a0.y, a0.z, a0.w, a1.x, a1.y, a1.z, a1.w};
#pragma unroll
                for (int j = 0; j < DD; ++j)
#pragma unroll
                    for (int m = 0; m < DD; ++m)
                        Ep[j][m] = fmaf(arow[j], tmp[i][m], Ep[j][m]);
            }
        }
#pragma unroll
        for (int i = 0; i < DD; ++i)
#pragma unroll
            for (int l = 0; l < DD; ++l) E[i][l] = Ep[i][l];
    }
    float diag = 0.0f;
#pragma unroll
    for (int i = 0; i < DD; ++i)
#pragma unroll
        for (int l = 0; l < DD; ++l) diag += (i * DD + l == lane) ? E[i][l] : 0.0f;
#pragma unroll
    for (int off = 32; off >= 1; off >>= 1) diag += __shfl_xor(diag, off, 64);
    if (lane == 0) {
        float tr = diag;
        out[2 * b]     = logf(fabsf(tr)) + 64.0f * 1.3862943611198906f;
        out[2 * b + 1] = (tr < 0.0f) ? 3.14159265358979323846f : 0.0f;
    }
}

extern "C" void kernel_launch(void* const* d_in, const int* in_sizes, int n_in,
                              void* d_out, int out_size, void* d_ws, size_t ws_size,
                              hipStream_t stream) {
    const int*   qn  = (const int*)d_in[0];
    const float* T   = (const float*)d_in[1];
    float*       out = (float*)d_out;
    const int B = in_sizes[0] / (2 * NSITES);
    const size_t WS_F8 = (size_t)NPAIRS * 16 * 4 * 64 * 16;  // 2 MB
    if (ws_size >= WS_F8) {
        uint4* Mf8 = (uint4*)d_ws;
        mpdo_prep2f8<<<dim3(NPAIRS * 16), dim3(64), 0, stream>>>(T, Mf8);
        mpdo_mfmaDC<<<dim3(B), dim3(64), 0, stream>>>(qn, Mf8, out);
    } else {
        mpdo_chain<<<dim3(B), dim3(64), 0, stream>>>(qn, T, out);
    }
}

// Round 14
// 27.537 us; speedup vs baseline: 1.3475x; 1.2751x over previous
//
#include <hip/hip_runtime.h>
#include <math.h>

// MPDO chain via MFMA + fp8 DELTA pair table, FULLY UNROLLED main loop.
//   per b: edge = Pi_t M_t (64x64); out = log(tr(edge))
//
// Ledger: issue-work null (R8/R9), wave-count null (R4/R6), split-k neg
// (R10), dual-chain neg (R12/R13), >L2 table neg (R7), bytes small (R11).
// R14 tests the last untested lever: the rolled loop itself. Full unroll of
// the 32 steps (compile-time pair indices) gives the compiler a straight-line
// ~2000-instr window to software-pipeline: loads hoisted across steps,
// counted vmcnt waits, relayout interleaved into MFMA shadows.
// fp8-delta step (R11-verified): X <- X + D^T X, D = (1/16)P - I in e4m3,
// identity carried exactly in f32 C-operand. Scale 4^-64 -> log += 64*ln4.
// Fallback: ws < 2MB -> verified fp32 VALU kernel.

#define NSITES 64
#define NPAIRS 32

typedef float f32x16 __attribute__((ext_vector_type(16)));

// pack 4 f32 -> 1 dword of 4 fp8 e4m3
#define PACK4(P, A0, A1, A2, A3)                                               \
    asm("v_cvt_pk_fp8_f32 %0, %1, %2" : "=v"(P) : "v"(A0), "v"(A1));           \
    asm("v_cvt_pk_fp8_f32 %0, %1, %2 op_sel:[0,0,1]" : "+v"(P) : "v"(A2), "v"(A3));

// ---------- prep2f8: D^T = (1/16)P^T - I in fp8 (verified R11) ----------
__global__ __launch_bounds__(64)
void mpdo_prep2f8(const float* __restrict__ T, uint4* __restrict__ Mf8) {
    const int blk = blockIdx.x;
    const int pair = blk >> 4, combo = blk & 15;
    const int c0 = combo >> 2, c1 = combo & 3;
    const int ir0 = c0 >> 1, ic0 = c0 & 1, ir1 = c1 >> 1, ic1 = c1 & 1;
    const int lane = threadIdx.x;
    const int site0 = 2 * pair, site1 = 2 * pair + 1;

    __shared__ float sT0[256], sT1[256], sT2[256], sT3[256];
    __shared__ float sPA[16 * 64], sPB[16 * 64];

    *(float4*)&sT0[lane * 4] = *(const float4*)(T + ((size_t)(site0 * 2 + ir0)) * 256 + lane * 4);
    *(float4*)&sT1[lane * 4] = *(const float4*)(T + ((size_t)(site0 * 2 + ic0)) * 256 + lane * 4);
    *(float4*)&sT2[lane * 4] = *(const float4*)(T + ((size_t)(site1 * 2 + ir1)) * 256 + lane * 4);
    *(float4*)&sT3[lane * 4] = *(const float4*)(T + ((size_t)(site1 * 2 + ic1)) * 256 + lane * 4);
    __syncthreads();

    {
        const int i = lane >> 3, j = lane & 7;
        float pa[4][4], pb[4][4];
#pragma unroll
        for (int k = 0; k < 4; ++k)
#pragma unroll
            for (int jp = 0; jp < 4; ++jp) { pa[k][jp] = 0.0f; pb[k][jp] = 0.0f; }
#pragma unroll
        for (int a = 0; a < 8; ++a) {
            float4 x0 = *(const float4*)&sT0[(i * 8 + a) * 4];
            float4 y0 = *(const float4*)&sT2[(a * 8 + j) * 4];
            float4 x1 = *(const float4*)&sT1[(i * 8 + a) * 4];
            float4 y1 = *(const float4*)&sT3[(a * 8 + j) * 4];
            const float xk0[4] = {x0.x, x0.y, x0.z, x0.w};
            const float yj0[4] = {y0.x, y0.y, y0.z, y0.w};
            const float xk1[4] = {x1.x, x1.y, x1.z, x1.w};
            const float yj1[4] = {y1.x, y1.y, y1.z, y1.w};
#pragma unroll
            for (int k = 0; k < 4; ++k)
#pragma unroll
                for (int jp = 0; jp < 4; ++jp) {
                    pa[k][jp] = fmaf(xk0[k], yj0[jp], pa[k][jp]);
                    pb[k][jp] = fmaf(xk1[k], yj1[jp], pb[k][jp]);
                }
        }
#pragma unroll
        for (int k = 0; k < 4; ++k)
#pragma unroll
            for (int jp = 0; jp < 4; ++jp) {
                sPA[(k * 4 + jp) * 64 + lane] = pa[k][jp];
                sPB[(k * 4 + jp) * 64 + lane] = pb[k][jp];
            }
    }
    __syncthreads();

    const int h = lane >> 5, r = lane & 31, m = r & 7, j2 = r >> 3;
    float acc[8][8];
#pragma unroll
    for (int f = 0; f < 8; ++f)
#pragma unroll
        for (int e = 0; e < 8; ++e) acc[f][e] = 0.0f;

#pragma unroll 4
    for (int c = 0; c < 16; ++c) {
        float paf[8], pbe[8];
#pragma unroll
        for (int ti = 0; ti < 2; ++ti)
#pragma unroll
            for (int kt = 0; kt < 4; ++kt)
                paf[ti * 4 + kt] = sPA[c * 64 + (2 * kt + h) * 8 + (4 * ti + j2)];
#pragma unroll
        for (int e = 0; e < 8; ++e) pbe[e] = sPB[c * 64 + e * 8 + m];
#pragma unroll
        for (int f = 0; f < 8; ++f)
#pragma unroll
            for (int e = 0; e < 8; ++e)
                acc[f][e] = fmaf(paf[f], pbe[e], acc[f][e]);
    }

#pragma unroll
    for (int fp = 0; fp < 4; ++fp) {
        unsigned d[4];
#pragma unroll
        for (int s = 0; s < 2; ++s) {
            const int f = 2 * fp + s;
            const int ti = f >> 2, kt = f & 3;
            float Fv[8];
#pragma unroll
            for (int e = 0; e < 8; ++e) {
                float w = acc[f][e] * 0.0625f;
                if (32 * ti + r == 16 * kt + 8 * h + e) w -= 1.0f;
                Fv[e] = w;
            }
            PACK4(d[2 * s],     Fv[0], Fv[1], Fv[2], Fv[3])
            PACK4(d[2 * s + 1], Fv[4], Fv[5], Fv[6], Fv[7])
        }
        Mf8[((size_t)(pair * 16 + combo) * 4 + fp) * 64 + lane] =
            make_uint4(d[0], d[1], d[2], d[3]);
    }
}

// ---------- main: 1 wave/b, 32 steps FULLY UNROLLED ----------
__global__ __launch_bounds__(64, 1)
void mpdo_mfmaU(const int* __restrict__ qn, const uint4* __restrict__ Mf8,
                float* __restrict__ out) {
    const int b = blockIdx.x;
    const int lane = threadIdx.x;
    const int* qb = qn + (size_t)b * (2 * NSITES);
    const int pi = lane & 31;
    const int pc = (qb[2 * pi] << 3) | (qb[64 + 2 * pi] << 2) |
                   (qb[2 * pi + 1] << 1) | (qb[64 + 2 * pi + 1]);
    const unsigned long long m3 = __ballot(pc & 8);
    const unsigned long long m2 = __ballot(pc & 4);
    const unsigned long long m1 = __ballot(pc & 2);
    const unsigned long long m0 = __ballot(pc & 1);
    const int col = lane & 31, hh = lane >> 5;
    const int laneoff = lane * 16;

    f32x16 acc[2][2];   // X, C-layout
#pragma unroll
    for (int rt = 0; rt < 2; ++rt)
#pragma unroll
        for (int ct = 0; ct < 2; ++ct)
#pragma unroll
            for (int g = 0; g < 16; ++g) {
                int row = (g & 3) + 8 * (g >> 2) + 4 * hh;
                acc[rt][ct][g] = (rt == ct && row == col) ? 1.0f : 0.0f;
            }

    const char* Mbase = (const char*)Mf8;
    uint4 A0[4], A1[4], A2[4];

#define COMBO(T_) ((int)(((((m3) >> (T_)) & 1ull) << 3) | ((((m2) >> (T_)) & 1ull) << 2) | \
                         ((((m1) >> (T_)) & 1ull) << 1) | (((m0) >> (T_)) & 1ull)))
#define LOADF(DST, PIDX)                                                       \
    {                                                                          \
        int c_ = COMBO(PIDX);                                                  \
        const char* nb_ = Mbase + (((size_t)(PIDX) * 16 + c_) << 12) + laneoff;\
        _Pragma("unroll")                                                      \
        for (int fp = 0; fp < 4; ++fp)                                         \
            DST[fp] = *(const uint4*)(nb_ + fp * 1024);                        \
    }
#define A64(CUR, F)                                                            \
    (((F) & 1) ? (((unsigned long long)CUR[(F) >> 1].w << 32) | CUR[(F) >> 1].z) \
               : (((unsigned long long)CUR[(F) >> 1].y << 32) | CUR[(F) >> 1].x))

// one fp8-delta step; T_ is a compile-time literal here
#define SITE_BODY(T_, CUR, NXT)                                               \
    {                                                                         \
        if ((T_) + 2 < 32) { LOADF(NXT, (T_) + 2) }                           \
        unsigned bf[4][2][2];                                                 \
        _Pragma("unroll")                                                     \
        for (int rt = 0; rt < 2; ++rt)                                        \
            _Pragma("unroll")                                                 \
            for (int ct = 0; ct < 2; ++ct) {                                  \
                unsigned u, v, u2, v2;                                        \
                PACK4(u,  acc[rt][ct][0],  acc[rt][ct][1],                    \
                          acc[rt][ct][2],  acc[rt][ct][3])                    \
                PACK4(v,  acc[rt][ct][4],  acc[rt][ct][5],                    \
                          acc[rt][ct][6],  acc[rt][ct][7])                    \
                asm("v_permlane32_swap_b32 %0, %1" : "+v"(u), "+v"(v));       \
                bf[2 * rt][ct][0] = u; bf[2 * rt][ct][1] = v;                 \
                PACK4(u2, acc[rt][ct][8],  acc[rt][ct][9],                    \
                          acc[rt][ct][10], acc[rt][ct][11])                   \
                PACK4(v2, acc[rt][ct][12], acc[rt][ct][13],                   \
                          acc[rt][ct][14], acc[rt][ct][15])                   \
                asm("v_permlane32_swap_b32 %0, %1" : "+v"(u2), "+v"(v2));     \
                bf[2 * rt + 1][ct][0] = u2; bf[2 * rt + 1][ct][1] = v2;       \
            }                                                                 \
        _Pragma("unroll")                                                     \
        for (int ti = 0; ti < 2; ++ti)                                        \
            _Pragma("unroll")                                                 \
            for (int tj = 0; tj < 2; ++tj) {                                  \
                f32x16 d = acc[ti][tj];                                       \
                _Pragma("unroll")                                             \
                for (int kt = 0; kt < 4; ++kt) {                              \
                    unsigned long long av = A64(CUR, ti * 4 + kt);            \
                    unsigned long long bv =                                   \
                        ((unsigned long long)bf[kt][tj][1] << 32) |           \
                        bf[kt][tj][0];                                        \
                    d = __builtin_amdgcn_mfma_f32_32x32x16_fp8_fp8(           \
                        (long)av, (long)bv, d, 0, 0, 0);                      \
                }                                                             \
                acc[ti][tj] = d;                                              \
            }                                                                 \
    }

    LOADF(A0, 0)
    LOADF(A1, 1)

    // fully unrolled: step t uses A[t%3], prefetches t+2 into A[(t+2)%3]
    SITE_BODY(0,  A0, A2) SITE_BODY(1,  A1, A0) SITE_BODY(2,  A2, A1)
    SITE_BODY(3,  A0, A2) SITE_BODY(4,  A1, A0) SITE_BODY(5,  A2, A1)
    SITE_BODY(6,  A0, A2) SITE_BODY(7,  A1, A0) SITE_BODY(8,  A2, A1)
    SITE_BODY(9,  A0, A2) SITE_BODY(10, A1, A0) SITE_BODY(11, A2, A1)
    SITE_BODY(12, A0, A2) SITE_BODY(13, A1, A0) SITE_BODY(14, A2, A1)
    SITE_BODY(15, A0, A2) SITE_BODY(16, A1, A0) SITE_BODY(17, A2, A1)
    SITE_BODY(18, A0, A2) SITE_BODY(19, A1, A0) SITE_BODY(20, A2, A1)
    SITE_BODY(21, A0, A2) SITE_BODY(22, A1, A0) SITE_BODY(23, A2, A1)
    SITE_BODY(24, A0, A2) SITE_BODY(25, A1, A0) SITE_BODY(26, A2, A1)
    SITE_BODY(27, A0, A2) SITE_BODY(28, A1, A0) SITE_BODY(29, A2, A1)
    SITE_BODY(30, A0, A2) SITE_BODY(31, A1, A0)
#undef SITE_BODY
#undef LOADF
#undef A64
#undef COMBO

    // trace (X = full product transposed; trace invariant)
    float diag = 0.0f;
#pragma unroll
    for (int tt = 0; tt < 2; ++tt)
#pragma unroll
        for (int g = 0; g < 16; ++g) {
            int row = (g & 3) + 8 * (g >> 2) + 4 * hh;
            if (row == col) diag += acc[tt][tt][g];
        }
#pragma unroll
    for (int off = 32; off >= 1; off >>= 1)
        diag += __shfl_xor(diag, off, 64);

    if (lane == 0) {
        float tr = diag;
        float re = logf(fabsf(tr)) + 64.0f * 1.3862943611198906f;  // undo 4^-64
        float im = (tr < 0.0f) ? 3.14159265358979323846f : 0.0f;
        out[2 * b]     = re;
        out[2 * b + 1] = im;
    }
}

// ---------- fallback fp32 VALU kernel (verified R2) ----------
#define DD 8
#define KCHI 4
__global__ __launch_bounds__(64, 1)
void mpdo_chain(const int* __restrict__ qn, const float* __restrict__ T,
                float* __restrict__ out) {
    const int b = blockIdx.x;
    const int lane = threadIdx.x;
    __shared__ float sA[KCHI][DD][DD];
    __shared__ float sB[KCHI][DD][DD];
    float E[DD][DD];
#pragma unroll
    for (int i = 0; i < DD; ++i)
#pragma unroll
        for (int l = 0; l < DD; ++l) E[i][l] = (i * DD + l == lane) ? 1.0f : 0.0f;
    const int* qb = qn + (size_t)b * (2 * NSITES);
    int ir0 = qb[0], ic0 = qb[NSITES];
    float4 aP = *reinterpret_cast<const float4*>(T + (size_t)ir0 * 256 + lane * 4);
    float4 bP = *reinterpret_cast<const float4*>(T + (size_t)ic0 * 256 + lane * 4);
    const int li = lane >> 3, lj = lane & 7;
#pragma unroll 1
    for (int site = 0; site < NSITES; ++site) {
        __syncthreads();
        sA[0][li][lj] = 0.5f * aP.x; sA[1][li][lj] = 0.5f * aP.y;
        sA[2][li][lj] = 0.5f * aP.z; sA[3][li][lj] = 0.5f * aP.w;
        sB[0][li][lj] = 0.5f * bP.x; sB[1][li][lj] = 0.5f * bP.y;
        sB[2][li][lj] = 0.5f * bP.z; sB[3][li][lj] = 0.5f * bP.w;
        __syncthreads();
        if (site + 1 < NSITES) {
            int irn = qb[site + 1], icn = qb[NSITES + site + 1];
            aP = *reinterpret_cast<const float4*>(T + ((size_t)(site + 1) * 2 + irn) * 256 + lane * 4);
            bP = *reinterpret_cast<const float4*>(T + ((size_t)(site + 1) * 2 + icn) * 256 + lane * 4);
        }
        float Ep[DD][DD];
#pragma unroll
        for (int j = 0; j < DD; ++j)
#pragma unroll
            for (int m = 0; m < DD; ++m) Ep[j][m] = 0.0f;
#pragma unroll 1
        for (int k = 0; k < KCHI; ++k) {
            float tmp[DD][DD];
#pragma unroll
            for (int l = 0; l < DD; ++l) {
                const float4* bp = reinterpret_cast<const float4*>(&sB[k][l][0]);
                float4 b0 = bp[0], b1 = bp[1];
                float brow[DD] = {b0.x, b0.y, b0.z, b0.w, b1.x, b1.y, b1.z, b1.w};
                if (l == 0) {
#pragma unroll
                    for (int i = 0; i < DD; ++i)
#pragma unroll
                        for (int m = 0; m < DD; ++m) tmp[i][m] = E[i][0] * brow[m];
                } else {
#pragma unroll
                    for (int i = 0; i < DD; ++i)
#pragma unroll
                        for (int m = 0; m < DD; ++m)
                            tmp[i][m] = fmaf(E[i][l], brow[m], tmp[i][m]);
                }
            }
#pragma unroll
            for (int i = 0; i < DD; ++i) {
                const float4* ap = reinterpret_cast<const float4*>(&sA[k][i][0]);
                float4 a0 = ap[0], a1 = ap[1];
                float arow[DD] = {a0.x, a0.y, a0.z, a0.w, a1.x, a1.y, a1.z, a1.w};
#pragma unroll
                for (int j = 0; j < DD; ++j)
#pragma unroll
                    for (int m = 0; m < DD; ++m)
                        Ep[j][m] = fmaf(arow[j], tmp[i][m], Ep[j][m]);
            }
        }
#pragma unroll
        for (int i = 0; i < DD; ++i)
#pragma unroll
            for (int l = 0; l < DD; ++l) E[i][l] = Ep[i][l];
    }
    float diag = 0.0f;
#pragma unroll
    for (int i = 0; i < DD; ++i)
#pragma unroll
        for (int l = 0; l < DD; ++l) diag += (i * DD + l == lane) ? E[i][l] : 0.0f;
#pragma unroll
    for (int off = 32; off >= 1; off >>= 1) diag += __shfl_xor(diag, off, 64);
    if (lane == 0) {
        float tr = diag;
        out[2 * b]     = logf(fabsf(tr)) + 64.0f * 1.3862943611198906f;
        out[2 * b + 1] = (tr < 0.0f) ? 3.14159265358979323846f : 0.0f;
    }
}

extern "C" void kernel_launch(void* const* d_in, const int* in_sizes, int n_in,
                              void* d_out, int out_size, void* d_ws, size_t ws_size,
                              hipStream_t stream) {
    const int*   qn  = (const int*)d_in[0];
    const float* T   = (const float*)d_in[1];
    float*       out = (float*)d_out;
    const int B = in_sizes[0] / (2 * NSITES);
    const size_t WS_F8 = (size_t)NPAIRS * 16 * 4 * 64 * 16;  // 2 MB
    if (ws_size >= WS_F8) {
        uint4* Mf8 = (uint4*)d_ws;
        mpdo_prep2f8<<<dim3(NPAIRS * 16), dim3(64), 0, stream>>>(T, Mf8);
        mpdo_mfmaU<<<dim3(B), dim3(64), 0, stream>>>(qn, Mf8, out);
    } else {
        mpdo_chain<<<dim3(B), dim3(64), 0, stream>>>(qn, T, out);
    }
}

// Round 15
// 25.999 us; speedup vs baseline: 1.4272x; 1.0591x over previous
//
#include <hip/hip_runtime.h>
#include <math.h>

// MPDO chain via K=64 scaled-MFMA fp8 DELTA pair table, fully unrolled.
//   per b: edge = Pi_t M_t (64x64); out = log(tr(edge))
//
// R14 (27.5us): full unroll fixed the scheduling window. R15 attacks the MFMA
// floor: mfma_scale_f32_32x32x64_f8f6f4 (fp8, unit scales) does a tile's whole
// K=64 contraction in ONE instr (~69cyc/SIMD vs 4x32cyc) -> 4 MFMA/step
// (was 16), chain depth 4 -> 1.
//   A-frag(D^T): row=lane&31, k=32*(lane>>5)+e (K-extension of the verified
//   32x32x16 pattern). B built from acc by PACK4 + permlane32_swap:
//   BV[2q]=[p0_lo,p1_lo], BV[2q+1]=[p0_hi,p1_hi] -> e=8q+{0..3}/{4..7}.
// fp8-delta (R11): X <- X + D^T X, D = (1/16)P - I in e4m3; identity carried
// exactly in f32 C-operand. Scale 4^-64 -> log += 64*ln4.
// Fallback: ws < 2MB -> verified fp32 VALU kernel.

#define NSITES 64
#define NPAIRS 32

typedef float f32x16 __attribute__((ext_vector_type(16)));
typedef int   i32x8  __attribute__((ext_vector_type(8)));

union AFrag { uint4 q[2]; i32x8 v; };

// pack 4 f32 -> 1 dword of 4 fp8 e4m3 (bytes 0..3)
#define PACK4(P, A0, A1, A2, A3)                                               \
    asm("v_cvt_pk_fp8_f32 %0, %1, %2" : "=v"(P) : "v"(A0), "v"(A1));           \
    asm("v_cvt_pk_fp8_f32 %0, %1, %2 op_sel:[0,0,1]" : "+v"(P) : "v"(A2), "v"(A3));

#define MFMA64(A, B, C)                                                        \
    __builtin_amdgcn_mfma_scale_f32_32x32x64_f8f6f4(                           \
        (A), (B), (C), 0, 0, 0, 0x7F7F7F7F, 0, 0x7F7F7F7F)

// ---------- prep2f8k: D^T = (1/16)P^T - I in fp8, K=64 A-frag layout ----------
// lane l, ti, elem e (0..31): D^T[32*ti + (l&31)][32*(l>>5) + e]
__global__ __launch_bounds__(64)
void mpdo_prep2f8k(const float* __restrict__ T, uint4* __restrict__ Mf8) {
    const int blk = blockIdx.x;              // 32 pairs * 16 combos
    const int pair = blk >> 4, combo = blk & 15;
    const int c0 = combo >> 2, c1 = combo & 3;
    const int ir0 = c0 >> 1, ic0 = c0 & 1, ir1 = c1 >> 1, ic1 = c1 & 1;
    const int lane = threadIdx.x;
    const int site0 = 2 * pair, site1 = 2 * pair + 1;

    __shared__ float sT0[256], sT1[256], sT2[256], sT3[256];
    __shared__ float sPA[16 * 64], sPB[16 * 64];

    *(float4*)&sT0[lane * 4] = *(const float4*)(T + ((size_t)(site0 * 2 + ir0)) * 256 + lane * 4);
    *(float4*)&sT1[lane * 4] = *(const float4*)(T + ((size_t)(site0 * 2 + ic0)) * 256 + lane * 4);
    *(float4*)&sT2[lane * 4] = *(const float4*)(T + ((size_t)(site1 * 2 + ir1)) * 256 + lane * 4);
    *(float4*)&sT3[lane * 4] = *(const float4*)(T + ((size_t)(site1 * 2 + ic1)) * 256 + lane * 4);
    __syncthreads();

    {   // PA_c[i][j] = sum_a Tr0[i][a][k]*Tr1[a][j][jp]; PB analogous
        const int i = lane >> 3, j = lane & 7;
        float pa[4][4], pb[4][4];
#pragma unroll
        for (int k = 0; k < 4; ++k)
#pragma unroll
            for (int jp = 0; jp < 4; ++jp) { pa[k][jp] = 0.0f; pb[k][jp] = 0.0f; }
#pragma unroll
        for (int a = 0; a < 8; ++a) {
            float4 x0 = *(const float4*)&sT0[(i * 8 + a) * 4];
            float4 y0 = *(const float4*)&sT2[(a * 8 + j) * 4];
            float4 x1 = *(const float4*)&sT1[(i * 8 + a) * 4];
            float4 y1 = *(const float4*)&sT3[(a * 8 + j) * 4];
            const float xk0[4] = {x0.x, x0.y, x0.z, x0.w};
            const float yj0[4] = {y0.x, y0.y, y0.z, y0.w};
            const float xk1[4] = {x1.x, x1.y, x1.z, x1.w};
            const float yj1[4] = {y1.x, y1.y, y1.z, y1.w};
#pragma unroll
            for (int k = 0; k < 4; ++k)
#pragma unroll
                for (int jp = 0; jp < 4; ++jp) {
                    pa[k][jp] = fmaf(xk0[k], yj0[jp], pa[k][jp]);
                    pb[k][jp] = fmaf(xk1[k], yj1[jp], pb[k][jp]);
                }
        }
#pragma unroll
        for (int k = 0; k < 4; ++k)
#pragma unroll
            for (int jp = 0; jp < 4; ++jp) {
                sPA[(k * 4 + jp) * 64 + lane] = pa[k][jp];
                sPB[(k * 4 + jp) * 64 + lane] = pb[k][jp];
            }
    }
    __syncthreads();

    const int h = lane >> 5, r = lane & 31, m = r & 7, j2 = r >> 3;
    // acc2[ti][e'] = P^T[32ti+r][32h+e'] = P[32h+e'][32ti+r]
    //   P row 32h+e' = i*8+l: i = 4h+(e'>>3), l = e'&7
    //   P col 32ti+r = j*8+m: j = 4ti+j2,    m = r&7
    float acc2[2][32];
#pragma unroll
    for (int ti = 0; ti < 2; ++ti)
#pragma unroll
        for (int e = 0; e < 32; ++e) acc2[ti][e] = 0.0f;

#pragma unroll 4
    for (int c = 0; c < 16; ++c) {
        float pav[2][4], pbv[8];
#pragma unroll
        for (int ti = 0; ti < 2; ++ti)
#pragma unroll
            for (int ii = 0; ii < 4; ++ii)
                pav[ti][ii] = sPA[c * 64 + (4 * h + ii) * 8 + (4 * ti + j2)];
#pragma unroll
        for (int l = 0; l < 8; ++l) pbv[l] = sPB[c * 64 + l * 8 + m];
#pragma unroll
        for (int ti = 0; ti < 2; ++ti)
#pragma unroll
            for (int ii = 0; ii < 4; ++ii)
#pragma unroll
                for (int l = 0; l < 8; ++l)
                    acc2[ti][8 * ii + l] = fmaf(pav[ti][ii], pbv[l], acc2[ti][8 * ii + l]);
    }

    // store (1/16)P^T - I as fp8; entry frag order: [ti*2 + half] (half = dwords 0-3 / 4-7)
#pragma unroll
    for (int ti = 0; ti < 2; ++ti) {
        unsigned dw[8];
#pragma unroll
        for (int j = 0; j < 8; ++j) {
            float v[4];
#pragma unroll
            for (int s = 0; s < 4; ++s) {
                float wv = acc2[ti][4 * j + s] * 0.0625f;
                if (ti == h && (4 * j + s) == r) wv -= 1.0f;
                v[s] = wv;
            }
            PACK4(dw[j], v[0], v[1], v[2], v[3])
        }
        Mf8[((size_t)(pair * 16 + combo) * 4 + ti * 2 + 0) * 64 + lane] =
            make_uint4(dw[0], dw[1], dw[2], dw[3]);
        Mf8[((size_t)(pair * 16 + combo) * 4 + ti * 2 + 1) * 64 + lane] =
            make_uint4(dw[4], dw[5], dw[6], dw[7]);
    }
}

// ---------- main: 1 wave/b, 32 steps fully unrolled, 4 K=64 MFMA/step ----------
__global__ __launch_bounds__(64, 1)
void mpdo_mfmaK(const int* __restrict__ qn, const uint4* __restrict__ Mf8,
                float* __restrict__ out) {
    const int b = blockIdx.x;
    const int lane = threadIdx.x;
    const int* qb = qn + (size_t)b * (2 * NSITES);
    const int pi = lane & 31;
    const int pc = (qb[2 * pi] << 3) | (qb[64 + 2 * pi] << 2) |
                   (qb[2 * pi + 1] << 1) | (qb[64 + 2 * pi + 1]);
    const unsigned long long m3 = __ballot(pc & 8);
    const unsigned long long m2 = __ballot(pc & 4);
    const unsigned long long m1 = __ballot(pc & 2);
    const unsigned long long m0 = __ballot(pc & 1);
    const int col = lane & 31, hh = lane >> 5;
    const int laneoff = lane * 16;

    f32x16 acc[2][2];   // X, C-layout: row=32*rt+(g&3)+8*(g>>2)+4*hh, col=32*ct+col
#pragma unroll
    for (int rt = 0; rt < 2; ++rt)
#pragma unroll
        for (int ct = 0; ct < 2; ++ct)
#pragma unroll
            for (int g = 0; g < 16; ++g) {
                int row = (g & 3) + 8 * (g >> 2) + 4 * hh;
                acc[rt][ct][g] = (rt == ct && row == col) ? 1.0f : 0.0f;
            }

    const char* Mbase = (const char*)Mf8;
    AFrag A0[2], A1[2], A2[2];   // [ti]

#define COMBO(T_) ((int)(((((m3) >> (T_)) & 1ull) << 3) | ((((m2) >> (T_)) & 1ull) << 2) | \
                         ((((m1) >> (T_)) & 1ull) << 1) | (((m0) >> (T_)) & 1ull)))
#define LOADF(DST, PIDX)                                                       \
    {                                                                          \
        int c_ = COMBO(PIDX);                                                  \
        const char* nb_ = Mbase + (((size_t)(PIDX) * 16 + c_) << 12) + laneoff;\
        DST[0].q[0] = *(const uint4*)(nb_ + 0 * 1024);                         \
        DST[0].q[1] = *(const uint4*)(nb_ + 1 * 1024);                         \
        DST[1].q[0] = *(const uint4*)(nb_ + 2 * 1024);                         \
        DST[1].q[1] = *(const uint4*)(nb_ + 3 * 1024);                         \
    }

// B column CT as i32x8: BV[2q]=[p0_lo,p1_lo], BV[2q+1]=[p0_hi,p1_hi]
//   lane hh=0 gets rows 8q+{0..3}/{4..7} of block0; hh=1 same of block1.
#define MAKE_BCOL(BV, CT)                                                      \
    {                                                                          \
        _Pragma("unroll")                                                      \
        for (int q = 0; q < 4; ++q) {                                          \
            unsigned p0, p1;                                                   \
            PACK4(p0, acc[0][CT][4 * q + 0], acc[0][CT][4 * q + 1],            \
                      acc[0][CT][4 * q + 2], acc[0][CT][4 * q + 3])            \
            PACK4(p1, acc[1][CT][4 * q + 0], acc[1][CT][4 * q + 1],            \
                      acc[1][CT][4 * q + 2], acc[1][CT][4 * q + 3])            \
            asm("v_permlane32_swap_b32 %0, %1" : "+v"(p0), "+v"(p1));          \
            BV[2 * q] = (int)p0; BV[2 * q + 1] = (int)p1;                      \
        }                                                                      \
    }

// one fp8-delta step: X <- X + D^T X (C-in carries identity exactly)
#define SITE_BODY(T_, CUR, NXT)                                                \
    {                                                                          \
        if ((T_) + 2 < 32) { LOADF(NXT, (T_) + 2) }                            \
        i32x8 b0, b1;                                                          \
        MAKE_BCOL(b0, 0)                                                       \
        MAKE_BCOL(b1, 1)                                                       \
        acc[0][0] = MFMA64(CUR[0].v, b0, acc[0][0]);                           \
        acc[0][1] = MFMA64(CUR[0].v, b1, acc[0][1]);                           \
        acc[1][0] = MFMA64(CUR[1].v, b0, acc[1][0]);                           \
        acc[1][1] = MFMA64(CUR[1].v, b1, acc[1][1]);                           \
    }

    LOADF(A0, 0)
    LOADF(A1, 1)

    SITE_BODY(0,  A0, A2) SITE_BODY(1,  A1, A0) SITE_BODY(2,  A2, A1)
    SITE_BODY(3,  A0, A2) SITE_BODY(4,  A1, A0) SITE_BODY(5,  A2, A1)
    SITE_BODY(6,  A0, A2) SITE_BODY(7,  A1, A0) SITE_BODY(8,  A2, A1)
    SITE_BODY(9,  A0, A2) SITE_BODY(10, A1, A0) SITE_BODY(11, A2, A1)
    SITE_BODY(12, A0, A2) SITE_BODY(13, A1, A0) SITE_BODY(14, A2, A1)
    SITE_BODY(15, A0, A2) SITE_BODY(16, A1, A0) SITE_BODY(17, A2, A1)
    SITE_BODY(18, A0, A2) SITE_BODY(19, A1, A0) SITE_BODY(20, A2, A1)
    SITE_BODY(21, A0, A2) SITE_BODY(22, A1, A0) SITE_BODY(23, A2, A1)
    SITE_BODY(24, A0, A2) SITE_BODY(25, A1, A0) SITE_BODY(26, A2, A1)
    SITE_BODY(27, A0, A2) SITE_BODY(28, A1, A0) SITE_BODY(29, A2, A1)
    SITE_BODY(30, A0, A2) SITE_BODY(31, A1, A0)
#undef SITE_BODY
#undef MAKE_BCOL
#undef LOADF
#undef COMBO

    // trace (X = full product transposed; trace invariant)
    float diag = 0.0f;
#pragma unroll
    for (int tt = 0; tt < 2; ++tt)
#pragma unroll
        for (int g = 0; g < 16; ++g) {
            int row = (g & 3) + 8 * (g >> 2) + 4 * hh;
            if (row == col) diag += acc[tt][tt][g];
        }
#pragma unroll
    for (int off = 32; off >= 1; off >>= 1)
        diag += __shfl_xor(diag, off, 64);

    if (lane == 0) {
        float tr = diag;
        float re = logf(fabsf(tr)) + 64.0f * 1.3862943611198906f;  // undo 4^-64
        float im = (tr < 0.0f) ? 3.14159265358979323846f : 0.0f;
        out[2 * b]     = re;
        out[2 * b + 1] = im;
    }
}

// ---------- fallback fp32 VALU kernel (verified R2) ----------
#define DD 8
#define KCHI 4
__global__ __launch_bounds__(64, 1)
void mpdo_chain(const int* __restrict__ qn, const float* __restrict__ T,
                float* __restrict__ out) {
    const int b = blockIdx.x;
    const int lane = threadIdx.x;
    __shared__ float sA[KCHI][DD][DD];
    __shared__ float sB[KCHI][DD][DD];
    float E[DD][DD];
#pragma unroll
    for (int i = 0; i < DD; ++i)
#pragma unroll
        for (int l = 0; l < DD; ++l) E[i][l] = (i * DD + l == lane) ? 1.0f : 0.0f;
    const int* qb = qn + (size_t)b * (2 * NSITES);
    int ir0 = qb[0], ic0 = qb[NSITES];
    float4 aP = *reinterpret_cast<const float4*>(T + (size_t)ir0 * 256 + lane * 4);
    float4 bP = *reinterpret_cast<const float4*>(T + (size_t)ic0 * 256 + lane * 4);
    const int li = lane >> 3, lj = lane & 7;
#pragma unroll 1
    for (int site = 0; site < NSITES; ++site) {
        __syncthreads();
        sA[0][li][lj] = 0.5f * aP.x; sA[1][li][lj] = 0.5f * aP.y;
        sA[2][li][lj] = 0.5f * aP.z; sA[3][li][lj] = 0.5f * aP.w;
        sB[0][li][lj] = 0.5f * bP.x; sB[1][li][lj] = 0.5f * bP.y;
        sB[2][li][lj] = 0.5f * bP.z; sB[3][li][lj] = 0.5f * bP.w;
        __syncthreads();
        if (site + 1 < NSITES) {
            int irn = qb[site + 1], icn = qb[NSITES + site + 1];
            aP = *reinterpret_cast<const float4*>(T + ((size_t)(site + 1) * 2 + irn) * 256 + lane * 4);
            bP = *reinterpret_cast<const float4*>(T + ((size_t)(site + 1) * 2 + icn) * 256 + lane * 4);
        }
        float Ep[DD][DD];
#pragma unroll
        for (int j = 0; j < DD; ++j)
#pragma unroll
            for (int m = 0; m < DD; ++m) Ep[j][m] = 0.0f;
#pragma unroll 1
        for (int k = 0; k < KCHI; ++k) {
            float tmp[DD][DD];
#pragma unroll
            for (int l = 0; l < DD; ++l) {
                const float4* bp = reinterpret_cast<const float4*>(&sB[k][l][0]);
                float4 b0 = bp[0], b1 = bp[1];
                float brow[DD] = {b0.x, b0.y, b0.z, b0.w, b1.x, b1.y, b1.z, b1.w};
                if (l == 0) {
#pragma unroll
                    for (int i = 0; i < DD; ++i)
#pragma unroll
                        for (int m = 0; m < DD; ++m) tmp[i][m] = E[i][0] * brow[m];
                } else {
#pragma unroll
                    for (int i = 0; i < DD; ++i)
#pragma unroll
                        for (int m = 0; m < DD; ++m)
                            tmp[i][m] = fmaf(E[i][l], brow[m], tmp[i][m]);
                }
            }
#pragma unroll
            for (int i = 0; i < DD; ++i) {
                const float4* ap = reinterpret_cast<const float4*>(&sA[k][i][0]);
                float4 a0 = ap[0], a1 = ap[1];
                float arow[DD] = {a0.x, a0.y, a0.z, a0.w, a1.x, a1.y, a1.z, a1.w};
#pragma unroll
                for (int j = 0; j < DD; ++j)
#pragma unroll
                    for (int m = 0; m < DD; ++m)
                        Ep[j][m] = fmaf(arow[j], tmp[i][m], Ep[j][m]);
            }
        }
#pragma unroll
        for (int i = 0; i < DD; ++i)
#pragma unroll
            for (int l = 0; l < DD; ++l) E[i][l] = Ep[i][l];
    }
    float diag = 0.0f;
#pragma unroll
    for (int i = 0; i < DD; ++i)
#pragma unroll
        for (int l = 0; l < DD; ++l) diag += (i * DD + l == lane) ? E[i][l] : 0.0f;
#pragma unroll
    for (int off = 32; off >= 1; off >>= 1) diag += __shfl_xor(diag, off, 64);
    if (lane == 0) {
        float tr = diag;
        out[2 * b]     = logf(fabsf(tr)) + 64.0f * 1.3862943611198906f;
        out[2 * b + 1] = (tr < 0.0f) ? 3.14159265358979323846f : 0.0f;
    }
}

extern "C" void kernel_launch(void* const* d_in, const int* in_sizes, int n_in,
                              void* d_out, int out_size, void* d_ws, size_t ws_size,
                              hipStream_t stream) {
    const int*   qn  = (const int*)d_in[0];
    const float* T   = (const float*)d_in[1];
    float*       out = (float*)d_out;
    const int B = in_sizes[0] / (2 * NSITES);
    const size_t WS_F8 = (size_t)NPAIRS * 16 * 4 * 64 * 16;  // 2 MB
    if (ws_size >= WS_F8) {
        uint4* Mf8 = (uint4*)d_ws;
        mpdo_prep2f8k<<<dim3(NPAIRS * 16), dim3(64), 0, stream>>>(T, Mf8);
        mpdo_mfmaK<<<dim3(B), dim3(64), 0, stream>>>(qn, Mf8, out);
    } else {
        mpdo_chain<<<dim3(B), dim3(64), 0, stream>>>(qn, T, out);
    }
}